// Round 1
// baseline (154.887 us; speedup 1.0000x reference)
//
#include <hip/hip_runtime.h>
#include <stdint.h>

#define B_ROWS 16384
#define C_COLS 1000
#define D_DIM  2048
#define TM 128
#define TN 128
#define BK 64

typedef __bf16 bf16x8 __attribute__((ext_vector_type(8)));
typedef float  f32x4  __attribute__((ext_vector_type(4)));
typedef unsigned short u16;

__device__ __forceinline__ u16 f2bf(float f) {
  union { float f; uint32_t u; } v; v.f = f;
  return (u16)((v.u + 0x7FFFu + ((v.u >> 16) & 1u)) >> 16);
}

// ---------------------------------------------------------------------------
// Kernel 1: cast W -> bf16 (XOR-swizzled per 64-elem chunk) + row norms (f32)
// ---------------------------------------------------------------------------
__global__ __launch_bounds__(256)
void prep_w(const float* __restrict__ W, u16* __restrict__ Wb,
            float* __restrict__ norms) {
  const int r = blockIdx.x;          // W row, 0..999
  const int t = threadIdx.x;         // 256 threads, 8 elems each (2048/256)
  const float* row = W + (size_t)r * D_DIM;
  const int c = t * 8;
  float4 v0 = *reinterpret_cast<const float4*>(row + c);
  float4 v1 = *reinterpret_cast<const float4*>(row + c + 4);
  float ss = v0.x*v0.x + v0.y*v0.y + v0.z*v0.z + v0.w*v0.w
           + v1.x*v1.x + v1.y*v1.y + v1.z*v1.z + v1.w*v1.w;
  uint32_t p0 = (uint32_t)f2bf(v0.x) | ((uint32_t)f2bf(v0.y) << 16);
  uint32_t p1 = (uint32_t)f2bf(v0.z) | ((uint32_t)f2bf(v0.w) << 16);
  uint32_t p2 = (uint32_t)f2bf(v1.x) | ((uint32_t)f2bf(v1.y) << 16);
  uint32_t p3 = (uint32_t)f2bf(v1.z) | ((uint32_t)f2bf(v1.w) << 16);
  const int mask = (r & 7) << 3;     // swizzle within each 64-elem (128B) chunk
  uint4 val; val.x = p0; val.y = p1; val.z = p2; val.w = p3;
  *reinterpret_cast<uint4*>(Wb + (size_t)r * D_DIM + (c ^ mask)) = val;
  // block reduction for ||W_r||
  #pragma unroll
  for (int m = 32; m; m >>= 1) ss += __shfl_xor(ss, m);
  __shared__ float wss[4];
  if ((t & 63) == 0) wss[t >> 6] = ss;
  __syncthreads();
  if (t == 0) norms[r] = sqrtf(wss[0] + wss[1] + wss[2] + wss[3]);
}

// ---------------------------------------------------------------------------
// Kernel 2: logits = x * W^T + b   (bf16 MFMA, f32 out)
// 128x128 tile, BK=64, 4 waves (2x2 quadrants of 64x64), 16x16x32 MFMA
// ---------------------------------------------------------------------------
__global__ __launch_bounds__(256)
void gemm_bf16(const float* __restrict__ x, const u16* __restrict__ Wb,
               const float* __restrict__ bias, float* __restrict__ out) {
  __shared__ u16 lds[TM * BK + TN * BK];   // A then B, 32 KiB total

  // XCD-aware bijective swizzle (1024 blocks, %8==0)
  const int bid = blockIdx.x;
  const int cpx = gridDim.x >> 3;
  const int swz = (bid & 7) * cpx + (bid >> 3);
  const int tn = swz & 7;            // 8 n-tiles (1000 -> padded 1024)
  const int tm = swz >> 3;           // 128 m-tiles
  const int m0 = tm * TM;
  const int n0 = tn * TN;

  const int t = threadIdx.x;
  const int w = t >> 6;
  const int l = t & 63;
  const int wr = w >> 1, wc = w & 1;

  f32x4 acc[4][4];
  #pragma unroll
  for (int i = 0; i < 4; ++i)
    #pragma unroll
    for (int j = 0; j < 4; ++j)
      acc[i][j] = (f32x4){0.f, 0.f, 0.f, 0.f};

  const int ar = w * 32 + (l >> 4);        // A stage base row (+ i*4)
  const int ac4 = (l & 15) * 4;            // A stage col (4 f32)
  const float* aptr = x + (size_t)(m0 + ar) * D_DIM + ac4;

  for (int k0 = 0; k0 < D_DIM; k0 += BK) {
    // ---- stage B: global_load_lds dwordx4, linear dest (source pre-swizzled)
    #pragma unroll
    for (int i = 0; i < 4; ++i) {
      int ci = w * 4 + i;                  // 1KB chunk id, wave-uniform
      int br = ci * 8 + (l >> 3);          // B tile row 0..127
      int wrow = n0 + br; if (wrow >= C_COLS) wrow = C_COLS - 1;
      const char* src = (const char*)Wb + (size_t)wrow * (D_DIM * 2)
                        + k0 * 2 + (l & 7) * 16;
      void* dst = (void*)((char*)(lds + TM * BK) + ci * 1024);
      __builtin_amdgcn_global_load_lds(
          (const __attribute__((address_space(1))) void*)src,
          (__attribute__((address_space(3))) void*)dst, 16, 0, 0);
    }
    // ---- stage A: f32 load -> bf16 cvt -> swizzled ds_write (8B)
    #pragma unroll
    for (int i = 0; i < 8; ++i) {
      int r = ar + i * 4;
      float4 v = *reinterpret_cast<const float4*>(aptr + (size_t)(i * 4) * D_DIM + k0);
      ushort4 h;
      h.x = f2bf(v.x); h.y = f2bf(v.y); h.z = f2bf(v.z); h.w = f2bf(v.w);
      int sc = ac4 ^ ((r & 7) << 3);
      *reinterpret_cast<ushort4*>(&lds[r * BK + sc]) = h;
    }
    __syncthreads();
    // ---- compute: 2 x (8 ds_read_b128 + 16 MFMA)
    #pragma unroll
    for (int kk = 0; kk < BK; kk += 32) {
      const int kg = kk + ((l >> 4) << 3);
      bf16x8 af[4], bfr[4];
      #pragma unroll
      for (int mi = 0; mi < 4; ++mi) {
        int row = wr * 64 + mi * 16 + (l & 15);
        int col = kg ^ ((row & 7) << 3);
        af[mi] = *reinterpret_cast<const bf16x8*>(&lds[row * BK + col]);
      }
      #pragma unroll
      for (int ni = 0; ni < 4; ++ni) {
        int row = wc * 64 + ni * 16 + (l & 15);
        int col = kg ^ ((row & 7) << 3);
        bfr[ni] = *reinterpret_cast<const bf16x8*>(&lds[TM * BK + row * BK + col]);
      }
      #pragma unroll
      for (int mi = 0; mi < 4; ++mi)
        #pragma unroll
        for (int ni = 0; ni < 4; ++ni)
          acc[mi][ni] = __builtin_amdgcn_mfma_f32_16x16x32_bf16(
              af[mi], bfr[ni], acc[mi][ni], 0, 0, 0);
    }
    __syncthreads();
  }

  // ---- epilogue: + bias, bounds-checked store (C/D: col=lane&15, row=(lane>>4)*4+j)
  #pragma unroll
  for (int ni = 0; ni < 4; ++ni) {
    int col = n0 + wc * 64 + ni * 16 + (l & 15);
    if (col < C_COLS) {
      float bv = bias[col];
      #pragma unroll
      for (int mi = 0; mi < 4; ++mi) {
        int row0 = m0 + wr * 64 + mi * 16 + ((l >> 4) << 2);
        #pragma unroll
        for (int j = 0; j < 4; ++j)
          out[(size_t)(row0 + j) * C_COLS + col] = acc[mi][ni][j] + bv;
      }
    }
  }
}

// ---------------------------------------------------------------------------
// Kernel 3: per-row selectors -> selection_score  (1 wave per row)
// ---------------------------------------------------------------------------
__global__ __launch_bounds__(256)
void selector(const float* __restrict__ logits, const float* __restrict__ norms,
              const float* __restrict__ selw, const float* __restrict__ selt,
              const float* __restrict__ ethr, float* __restrict__ out) {
  __shared__ float nrm[C_COLS];
  const int t = threadIdx.x;
  for (int i = t; i < C_COLS; i += 256) nrm[i] = norms[i];
  __syncthreads();

  const int w = t >> 6, l = t & 63;
  const int row = blockIdx.x * 4 + w;
  const float* lp = logits + (size_t)row * C_COLS;

  float lg[16];
  float t1 = -3.4e38f, t2 = -3.4e38f, n1 = -3.4e38f, n2 = -3.4e38f;
  #pragma unroll
  for (int i = 0; i < 16; ++i) {
    int idx = l + i * 64;
    float v = (idx < C_COLS) ? lp[idx] : -3.4e38f;
    lg[i] = v;
    if (v > t1) { t2 = t1; t1 = v; } else if (v > t2) t2 = v;
    float nv = (idx < C_COLS) ? v / (nrm[idx] + 1e-8f) : -3.4e38f;
    if (nv > n1) { n2 = n1; n1 = nv; } else if (nv > n2) n2 = nv;
  }
  // wave-wide top-2 merge (raw + normalized)
  #pragma unroll
  for (int m = 1; m < 64; m <<= 1) {
    float o1 = __shfl_xor(t1, m), o2 = __shfl_xor(t2, m);
    if (o1 > t1) { t2 = fmaxf(t1, o2); t1 = o1; } else t2 = fmaxf(t2, o1);
    float p1 = __shfl_xor(n1, m), p2 = __shfl_xor(n2, m);
    if (p1 > n1) { n2 = fmaxf(n1, p2); n1 = p1; } else n2 = fmaxf(n2, p1);
  }
  const float mx = t1;  // true row max

  float S = 0.f, sq = 0.f;
  float ex[16];
  #pragma unroll
  for (int i = 0; i < 16; ++i) {
    int idx = l + i * 64;
    float e = (idx < C_COLS) ? __expf(lg[i] - mx) : 0.f;
    ex[i] = e; S += e; sq += e * e;
  }
  #pragma unroll
  for (int m = 1; m < 64; m <<= 1) { S += __shfl_xor(S, m); sq += __shfl_xor(sq, m); }

  float ent = 0.f;
  #pragma unroll
  for (int i = 0; i < 16; ++i) {
    int idx = l + i * 64;
    if (idx < C_COLS) {
      float p = ex[i] / S;
      ent += p * __logf(p + 1e-10f);
    }
  }
  #pragma unroll
  for (int m = 1; m < 64; m <<= 1) ent += __shfl_xor(ent, m);

  if (l == 0) {
    float sc0 = 1.f / S;               // SRMax: max prob = exp(0)/S
    float sc1 = 1.f - (S * S) / sq;    // SRDoctor: 1 - 1/sum(p^2)
    float sc2 = ent;                   // SREntropy (neg-entropy)
    float sc3 = n1 - n2;               // RLGeoM
    float sc4 = t1 - t2;               // RLConfM
    float ens = selw[0] * tanhf(sc0 - selt[0])
              + selw[1] * tanhf(sc1 - selt[1])
              + selw[2] * tanhf(sc2 - selt[2])
              + selw[3] * tanhf(sc3 - selt[3])
              + selw[4] * tanhf(sc4 - selt[4]);
    out[row] = tanhf(ens - ethr[0]);
  }
}

// ---------------------------------------------------------------------------
extern "C" void kernel_launch(void* const* d_in, const int* in_sizes, int n_in,
                              void* d_out, int out_size, void* d_ws, size_t ws_size,
                              hipStream_t stream) {
  const float* x    = (const float*)d_in[0];
  const float* W    = (const float*)d_in[1];
  const float* b    = (const float*)d_in[2];
  const float* selw = (const float*)d_in[3];
  const float* selt = (const float*)d_in[4];
  const float* ethr = (const float*)d_in[5];
  float* out = (float*)d_out;

  u16*   Wb    = (u16*)d_ws;                                     // 4,096,000 B
  float* norms = (float*)((char*)d_ws + (size_t)C_COLS * D_DIM * 2);  // +4,000 B

  prep_w<<<C_COLS, 256, 0, stream>>>(W, Wb, norms);
  gemm_bf16<<<(B_ROWS / TM) * 8, 256, 0, stream>>>(x, Wb, b, out);
  selector<<<B_ROWS / 4, 256, 0, stream>>>(out, norms, selw, selt, ethr,
                                           out + (size_t)B_ROWS * C_COLS);
}